// Round 8
// baseline (46.170 us; speedup 1.0000x reference)
//
#include <hip/hip_runtime.h>

#define NN   2048
#define EE   65536
#define EDIM 64
#define LL   5
#define TPK  524288   // total threads in pairs_kernel (512 blocks x 1024)

// Kernel 1: dotsT[l][e] = sum_d edge_attr[e][d] * edge_vector[l][d]  (fp16, transposed)
__global__ __launch_bounds__(256) void dots_kernel(
    const float* __restrict__ edge_attr,
    const float* __restrict__ edge_vector,
    _Float16* __restrict__ dotsT) {
  const int lane = threadIdx.x & 63;
  const int wib  = threadIdx.x >> 6;   // wave in block: 0..3
  const int dg   = lane & 15;          // d-group: 4 floats each
  const int es   = lane >> 4;          // edge within wave: 0..3
  const int e    = blockIdx.x * 16 + wib * 4 + es;

  const float4 a = *(const float4*)(edge_attr + e * EDIM + dg * 4);
  float d[LL];
#pragma unroll
  for (int l = 0; l < LL; ++l) {
    const float4 ev = *(const float4*)(edge_vector + l * EDIM + dg * 4);
    d[l] = a.x * ev.x + a.y * ev.y + a.z * ev.z + a.w * ev.w;
  }
#pragma unroll
  for (int s = 1; s <= 8; s <<= 1) {
#pragma unroll
    for (int l = 0; l < LL; ++l) d[l] += __shfl_xor(d[l], s, 64);
  }
  if (dg < LL) {
    const float dv = (dg == 0) ? d[0] : (dg == 1) ? d[1] : (dg == 2) ? d[2]
                   : (dg == 3) ? d[3] : d[4];
    dotsT[dg * EE + e] = (_Float16)dv;
  }
}

// Kernel 2: 8 pairs/thread (adr[40]+sum[8] ~ 55 live regs < 64 VGPR cap, so
// the compiler keeps indices in registers instead of re-reading ept per pass
// — R6/R7's hidden 5x index re-read was the TA wall). 512 WGs x 1024 thr;
// 128 KB LDS -> 1 WG/CU, 2 sequential WGs per CU.
__global__ __launch_bounds__(1024, 4) void pairs_kernel(
    const int* __restrict__ ept,
    const _Float16* __restrict__ dotsT,
    float* __restrict__ out) {
  __shared__ __align__(16) unsigned short tab[EE + 8];  // 128 KB + sentinel
  const int tid = blockIdx.x * 1024 + threadIdx.x;      // 0..TPK-1

  // ---- Load 40 indices (2 groups x 5 int4), convert to LDS byte addrs. ----
  int adr[40];       // slot (pair k, l) at adr[k*5+l]; invalid -> EE*2 (sentinel)
  unsigned cp0 = 0u; // packed 4-bit valid counts for pairs 0..7
#pragma unroll
  for (int g = 0; g < 2; ++g) {
    const size_t gid = (size_t)g * TPK + (size_t)tid;   // 4-pair group id
    const int4* p = (const int4*)(ept + gid * 20);
#pragma unroll
    for (int q = 0; q < 5; ++q) {
      const int4 v = p[q];
#pragma unroll
      for (int jj = 0; jj < 4; ++jj) {
        const int si = q * 4 + jj;                 // 0..19 within group
        const int k  = g * 4 + si / 5;             // pair 0..7 (compile-time)
        const int id = (jj == 0) ? v.x : (jj == 1) ? v.y : (jj == 2) ? v.z : v.w;
        adr[g * 20 + si] = (id < 0) ? (EE * 2) : (id * 2);
        cp0 += ((id >= 0) ? 1u : 0u) << (k * 4);
      }
    }
  }

  float sum[8];
#pragma unroll
  for (int k = 0; k < 8; ++k) sum[k] = 0.f;

  const char* tabb = (const char*)tab;
  if (threadIdx.x == 0) tab[EE] = 0;  // fp16 +0.0 sentinel (beyond staged range)

  // ---- 5 passes: stage plane l (128 KB), gather slots with that l. ----
#pragma unroll
  for (int l = 0; l < LL; ++l) {
    __syncthreads();  // prev pass reads done (and sentinel visible on l==0)
    const float4* src = (const float4*)(dotsT + (size_t)l * EE);
    float4* dst = (float4*)tab;
#pragma unroll
    for (int r = 0; r < 8; ++r)
      dst[r * 1024 + threadIdx.x] = src[r * 1024 + threadIdx.x];
    __syncthreads();
#pragma unroll
    for (int k = 0; k < 8; ++k)
      sum[k] += (float)*(const _Float16*)(tabb + adr[k * 5 + l]);
  }

  // ---- Finalize: divide by count, coalesced float4 stores. ----
#pragma unroll
  for (int g = 0; g < 2; ++g) {
    const size_t gid = (size_t)g * TPK + (size_t)tid;
    float rr[4];
#pragma unroll
    for (int j = 0; j < 4; ++j) {
      const int k = g * 4 + j;
      const unsigned cnt = (cp0 >> (k * 4)) & 15u;
      rr[j] = sum[k] / ((float)cnt + 1e-10f);  // cnt==0 -> sum==0 -> 0
    }
    ((float4*)out)[gid] = make_float4(rr[0], rr[1], rr[2], rr[3]);
  }
}

extern "C" void kernel_launch(void* const* d_in, const int* in_sizes, int n_in,
                              void* d_out, int out_size, void* d_ws, size_t ws_size,
                              hipStream_t stream) {
  // d_in order: x(unused), edge_attr, edge_vector, edge_paths_tensor, edge_paths_length(unused)
  const float* edge_attr   = (const float*)d_in[1];
  const float* edge_vector = (const float*)d_in[2];
  const int*   ept         = (const int*)d_in[3];
  float* out = (float*)d_out;
  _Float16* dotsT = (_Float16*)d_ws;  // L x E fp16 = 640 KB scratch

  dots_kernel<<<EE / 16, 256, 0, stream>>>(edge_attr, edge_vector, dotsT);

  // 512 WGs x 1024 threads, 8 pairs/thread; 1 WG/CU resident (128 KB LDS).
  pairs_kernel<<<512, 1024, 0, stream>>>(ept, dotsT, out);
}

// Round 9
// 40.792 us; speedup vs baseline: 1.1318x; 1.1318x over previous
//
#include <hip/hip_runtime.h>

#define NN   2048
#define EE   65536
#define EDIM 64
#define LL   5
#define TPK2 262144   // total threads in pairs_kernel (256 blocks x 1024)

// Kernel 1: dotsT[l][e] = sum_d edge_attr[e][d] * edge_vector[l][d]  (fp16, transposed)
__global__ __launch_bounds__(256) void dots_kernel(
    const float* __restrict__ edge_attr,
    const float* __restrict__ edge_vector,
    _Float16* __restrict__ dotsT) {
  const int lane = threadIdx.x & 63;
  const int wib  = threadIdx.x >> 6;   // wave in block: 0..3
  const int dg   = lane & 15;          // d-group: 4 floats each
  const int es   = lane >> 4;          // edge within wave: 0..3
  const int e    = blockIdx.x * 16 + wib * 4 + es;

  const float4 a = *(const float4*)(edge_attr + e * EDIM + dg * 4);
  float d[LL];
#pragma unroll
  for (int l = 0; l < LL; ++l) {
    const float4 ev = *(const float4*)(edge_vector + l * EDIM + dg * 4);
    d[l] = a.x * ev.x + a.y * ev.y + a.z * ev.z + a.w * ev.w;
  }
#pragma unroll
  for (int s = 1; s <= 8; s <<= 1) {
#pragma unroll
    for (int l = 0; l < LL; ++l) d[l] += __shfl_xor(d[l], s, 64);
  }
  if (dg < LL) {
    const float dv = (dg == 0) ? d[0] : (dg == 1) ? d[1] : (dg == 2) ? d[2]
                   : (dg == 3) ? d[3] : d[4];
    dotsT[dg * EE + e] = (_Float16)dv;
  }
}

// Kernel 2: 16 pairs/thread, indices packed 2-per-VGPR (u16 each, ids<65536)
// and PINNED live via asm barriers so the compiler cannot re-read ept per
// pass (R6-R8's hidden wall). Invalid slots gather tab[0]; since invalid l's
// are a suffix (l >= path length), the correction is a suffix-sum of the
// per-pass tab[0] values selected by the valid count.
__global__ __launch_bounds__(1024, 4) void pairs_kernel(
    const int* __restrict__ ept,
    const _Float16* __restrict__ dotsT,
    float* __restrict__ out) {
  __shared__ __align__(16) unsigned short tab[EE];  // exactly 128 KB
  const int tid = blockIdx.x * 1024 + threadIdx.x;  // 0..TPK2-1

  // ---- Load 80 indices, pack to u16 halves (invalid -> 0), count valids. ----
  unsigned pk[40];
  unsigned cp0 = 0u, cp1 = 0u;  // 4-bit valid counts, pairs 0..7 / 8..15
#pragma unroll
  for (int g = 0; g < 4; ++g) {
    const size_t gid = (size_t)g * TPK2 + (size_t)tid;
    const int4* p = (const int4*)(ept + gid * 20);
    int raw[20];
#pragma unroll
    for (int q = 0; q < 5; ++q) {
      const int4 v = p[q];
      raw[q * 4 + 0] = v.x; raw[q * 4 + 1] = v.y;
      raw[q * 4 + 2] = v.z; raw[q * 4 + 3] = v.w;
    }
#pragma unroll
    for (int s = 0; s < 20; ++s) {
      const int id = raw[s];
      const int k  = g * 4 + s / 5;          // global pair 0..15 (compile-time)
      const unsigned m = (id >= 0) ? 1u : 0u;
      if (k < 8) cp0 += m << (k * 4); else cp1 += m << ((k - 8) * 4);
      const unsigned e16 = (id < 0) ? 0u : (unsigned)id;
      const int sg = g * 20 + s;             // global slot = k*5 + l
      if ((sg & 1) == 0) pk[sg >> 1] = e16;
      else               pk[sg >> 1] |= (e16 << 16);
    }
  }
  // Pin packed indices + counts: downstream uses reference asm outputs, so
  // the compiler cannot rematerialize them as per-pass global re-reads.
  asm volatile("" : "+v"(pk[0]), "+v"(pk[1]), "+v"(pk[2]), "+v"(pk[3]),
                    "+v"(pk[4]), "+v"(pk[5]), "+v"(pk[6]), "+v"(pk[7]),
                    "+v"(pk[8]), "+v"(pk[9]), "+v"(pk[10]), "+v"(pk[11]),
                    "+v"(pk[12]), "+v"(pk[13]), "+v"(pk[14]), "+v"(pk[15]),
                    "+v"(pk[16]), "+v"(pk[17]), "+v"(pk[18]), "+v"(pk[19]));
  asm volatile("" : "+v"(pk[20]), "+v"(pk[21]), "+v"(pk[22]), "+v"(pk[23]),
                    "+v"(pk[24]), "+v"(pk[25]), "+v"(pk[26]), "+v"(pk[27]),
                    "+v"(pk[28]), "+v"(pk[29]), "+v"(pk[30]), "+v"(pk[31]),
                    "+v"(pk[32]), "+v"(pk[33]), "+v"(pk[34]), "+v"(pk[35]),
                    "+v"(pk[36]), "+v"(pk[37]), "+v"(pk[38]), "+v"(pk[39]),
                    "+v"(cp0), "+v"(cp1));

  float sum[16];
#pragma unroll
  for (int k = 0; k < 16; ++k) sum[k] = 0.f;
  float t0v[LL];  // tab[0] per pass (for suffix-sum correction)

  const char* tabb = (const char*)tab;

  // ---- 5 passes: stage plane l (128 KB), gather slots with that l. ----
#pragma unroll
  for (int l = 0; l < LL; ++l) {
    __syncthreads();  // previous pass's reads done before overwrite
    const float4* src = (const float4*)(dotsT + (size_t)l * EE);
    float4* dst = (float4*)tab;
#pragma unroll
    for (int r = 0; r < 8; ++r)
      dst[r * 1024 + threadIdx.x] = src[r * 1024 + threadIdx.x];
    __syncthreads();
    t0v[l] = (float)*(const _Float16*)tabb;  // broadcast read of tab[0]
#pragma unroll
    for (int k = 0; k < 16; ++k) {
      const int sg = k * LL + l;             // compile-time
      const unsigned r = pk[sg >> 1];
      const unsigned addr = (sg & 1) ? ((r >> 15) & 0x1fffeu)
                                     : ((r << 1) & 0x1fffeu);
      sum[k] += (float)*(const _Float16*)(tabb + addr);
    }
  }

  // ---- Suffix sums of tab0 per pass: S[m] = sum_{l>=m} t0v[l]. ----
  const float S4 = t0v[4];
  const float S3 = S4 + t0v[3];
  const float S2 = S3 + t0v[2];
  const float S1 = S2 + t0v[1];
  const float S0 = S1 + t0v[0];

  // ---- Finalize: subtract invalid-suffix correction, divide, store. ----
#pragma unroll
  for (int g = 0; g < 4; ++g) {
    const size_t gid = (size_t)g * TPK2 + (size_t)tid;
    float rr[4];
#pragma unroll
    for (int j = 0; j < 4; ++j) {
      const int k = g * 4 + j;
      const unsigned cnt = (((k < 8) ? cp0 : cp1) >> ((k & 7) * 4)) & 15u;
      const float corr = (cnt == 5) ? 0.f
                       : (cnt == 4) ? S4
                       : (cnt == 3) ? S3
                       : (cnt == 2) ? S2
                       : (cnt == 1) ? S1 : S0;
      rr[j] = (sum[k] - corr) / ((float)cnt + 1e-10f);  // cnt==0 -> 0
    }
    ((float4*)out)[gid] = make_float4(rr[0], rr[1], rr[2], rr[3]);
  }
}

extern "C" void kernel_launch(void* const* d_in, const int* in_sizes, int n_in,
                              void* d_out, int out_size, void* d_ws, size_t ws_size,
                              hipStream_t stream) {
  // d_in order: x(unused), edge_attr, edge_vector, edge_paths_tensor, edge_paths_length(unused)
  const float* edge_attr   = (const float*)d_in[1];
  const float* edge_vector = (const float*)d_in[2];
  const int*   ept         = (const int*)d_in[3];
  float* out = (float*)d_out;
  _Float16* dotsT = (_Float16*)d_ws;  // L x E fp16 = 640 KB scratch

  dots_kernel<<<EE / 16, 256, 0, stream>>>(edge_attr, edge_vector, dotsT);

  // 256 WGs x 1024 threads, 16 pairs/thread; 1 WG/CU resident (128 KB LDS).
  pairs_kernel<<<256, 1024, 0, stream>>>(ept, dotsT, out);
}